// Round 9
// baseline (142.906 us; speedup 1.0000x reference)
//
#include <hip/hip_runtime.h>
#include <hip/hip_bf16.h>
#include <math.h>

typedef __attribute__((ext_vector_type(8))) short short8;
typedef __attribute__((ext_vector_type(4))) float f32x4;
typedef __attribute__((ext_vector_type(16))) float f32x16;

__device__ __forceinline__ unsigned short f2bf(float f) {
    union { float f; unsigned u; } x; x.f = f;
    unsigned r = x.u + 0x7FFF + ((x.u >> 16) & 1);
    return (unsigned short)(r >> 16);
}

__device__ __forceinline__ short8 mk8(uint2 a, uint2 b) {
    union { uint2 u[2]; short8 s; } x;
    x.u[0] = a; x.u[1] = b;
    return x.s;
}

// ---------------- prep ----------------
// wp2n[tap<9][lane<64][j<8]: A32 for conv2: m=oc=lane&31, ic=(lane>>5)*8+j (16 ic)
// wp3n[tap<9][h<2][ot<2][lane<64][j<8]: A32 for conv3: oc=ot*32+(lane&31), ic=h*16+(lane>>5)*8+j
// wp1[s<2][lane<64][j<8]: conv1 16x16: s0: k=tap*4+ic (taps 0..7); s1: k<3 -> ic of tap8
// pjwt2[k<16][d<8][pos<64][o<4] = pjw[k][c=o*64+pos][d]
__global__ void k_prep(const float* __restrict__ w2, const float* __restrict__ w3,
    const float* g2, const float* be2, const float* m2, const float* v2, const float* cb2,
    const float* g3, const float* be3, const float* m3, const float* v3, const float* cb3,
    const float* __restrict__ w1,
    const float* g1, const float* be1, const float* m1, const float* v1, const float* cb1,
    const float* __restrict__ pjw,
    unsigned short* __restrict__ wp2, unsigned short* __restrict__ wp3,
    unsigned short* __restrict__ wp1,
    float* __restrict__ cst2, float* __restrict__ cst3, float* __restrict__ cst1,
    float* __restrict__ pjwt)
{
    int tid = blockIdx.x * 256 + threadIdx.x;
    if (tid < 4608) {
        int j = tid & 7, lane = (tid >> 3) & 63, tap = tid >> 9;
        int oc = lane & 31;
        int ic = ((lane >> 5) << 3) + j;
        wp2[tid] = f2bf(w2[(oc * 16 + ic) * 9 + tap]);
    } else if (tid < 23040) {
        int idx = tid - 4608;
        int j = idx & 7, lane = (idx >> 3) & 63;
        int ot = (idx >> 9) & 1, h = (idx >> 10) & 1, tap = idx >> 11;
        int oc = ot * 32 + (lane & 31);
        int ic = h * 16 + ((lane >> 5) << 3) + j;
        wp3[idx] = f2bf(w3[(oc * 32 + ic) * 9 + tap]);
    } else if (tid < 23136) {
        int c = tid - 23040;
        if (c < 32) {
            float inv = g2[c] * rsqrtf(v2[c] + 1e-5f);
            cst2[c] = inv;
            cst2[32 + c] = (cb2[c] - m2[c]) * inv + be2[c];
        } else {
            int c3 = c - 32;
            float inv = g3[c3] * rsqrtf(v3[c3] + 1e-5f);
            cst3[c3] = inv;
            cst3[64 + c3] = (cb3[c3] - m3[c3]) * inv + be3[c3];
        }
    } else if (tid < 24160) {
        int idx = tid - 23136;
        int j = idx & 7, lane = (idx >> 3) & 63, s = (idx >> 9) & 1;
        int k = ((lane >> 4) << 3) + j;
        int oc = lane & 15;
        float val = 0.f;
        if (s == 0) {
            int tap = k >> 2, ic = k & 3;
            if (ic < 3) val = w1[(oc * 3 + ic) * 9 + tap];
        } else {
            if (k < 3) val = w1[(oc * 3 + k) * 9 + 8];
        }
        wp1[idx] = f2bf(val);
    } else if (tid < 24176) {
        int c = tid - 24160;
        float inv = g1[c] * rsqrtf(v1[c] + 1e-5f);
        cst1[c] = inv;
        cst1[16 + c] = (cb1[c] - m1[c]) * inv + be1[c];
    } else if (tid < 56944) {
        int idx = tid - 24176;
        int o = idx & 3, pos = (idx >> 2) & 63, d = (idx >> 8) & 7, k = idx >> 11;
        pjwt[idx] = pjw[k * 2048 + (o * 64 + pos) * 8 + d];
    }
}

// ---------------- Fused, one block (512 thr) per image, 32x32x16 MFMA for conv2/3.
// LDS (58880 B, 2 blocks/CU):
//  [0,17952):      xs [34][66][4ic] bf16 (conv1 staging)
//  [0,20736):      h2t0..3 [18*18][8ic] bf16 (4 x 5184B, bordered)  -- after conv1
//  [20736,21888):  czs (512B) + partl (640B)
//  [21888,58880):  h1A/h1B [34*34][8ic] bf16 bordered (2 x 18496B)
//  [21888,39296):  feats [64 pos][68] f32 -- after conv2
__global__ __launch_bounds__(512, 4) void k_fused(
    const float* __restrict__ x,
    const unsigned short* __restrict__ wp1, const float* __restrict__ cst1,
    const unsigned short* __restrict__ wp2, const float* __restrict__ cst2,
    const unsigned short* __restrict__ wp3, const float* __restrict__ cst3,
    const float* __restrict__ pjwt, const float* __restrict__ pjb,
    const float* __restrict__ cw, const float* __restrict__ cbias,
    float* __restrict__ out)
{
    __shared__ __align__(16) unsigned char smem[58880];
    unsigned short* xs  = (unsigned short*)smem;
    unsigned short* h2t = (unsigned short*)smem;             // 4 arrays, stride 5184B
    float* czs   = (float*)(smem + 20736);
    float* partl = czs + 128;
    unsigned short* h1A = (unsigned short*)(smem + 21888);
    unsigned short* h1B = (unsigned short*)(smem + 40384);
    float* feats = (float*)(smem + 21888);

    int b = blockIdx.x, t = threadIdx.x;
    int lane = t & 63, w = t >> 6, q = lane >> 4, xl = lane & 15;
    const float* img = x + (size_t)b * 12288;

    // zero h1 borders (132 pos x 2 arrays, b128 each)
    if (t < 264) {
        int arr = t & 1, idx = t >> 1;
        int y, xx;
        if (idx < 34)       { y = 0;        xx = idx; }
        else if (idx < 68)  { y = 33;       xx = idx - 34; }
        else if (idx < 100) { y = idx - 67; xx = 0; }
        else                { y = idx - 99; xx = 33; }
        uint4 z = {0u, 0u, 0u, 0u};
        *(uint4*)((arr ? h1B : h1A) + (y * 34 + xx) * 8) = z;
    }

    // ======== conv1 (16x16x32): 3->16, pool -> h1A/h1B bordered ========
    short8 A10 = *(const short8*)(wp1 + (lane << 3));
    short8 A11 = *(const short8*)(wp1 + ((64 + lane) << 3));
    int t0 = 2 * q, t1 = 2 * q + 1;
    int dy0 = t0 / 3 - 1, dx0 = t0 % 3 - 1;
    int dy1 = t1 / 3 - 1, dx1 = t1 % 3 - 1;
    float inv1[4], bs1[4];
    #pragma unroll
    for (int reg = 0; reg < 4; ++reg) {
        inv1[reg] = cst1[q * 4 + reg];
        bs1[reg]  = cst1[16 + q * 4 + reg];
    }
    unsigned* h1w = (unsigned*)(q < 2 ? h1A : h1B);
    #pragma unroll 1
    for (int h = 0; h < 2; ++h) {
        if (h) __syncthreads();
        int y0 = h * 32 - 1;
        #pragma unroll 1
        for (int i = 0; i < 5; ++i) {
            int idx = t + i * 512;
            if (idx < 2244) {
                int y = idx / 66, xx = idx - y * 66;
                int gy = y0 + y, gx = xx - 1;
                float v0 = 0.f, v1 = 0.f, v2 = 0.f;
                if ((unsigned)gy < 64u && (unsigned)gx < 64u) {
                    const float* pb = img + gy * 64 + gx;
                    v0 = pb[0]; v1 = pb[4096]; v2 = pb[8192];
                }
                uint2 pk;
                pk.x = (unsigned)f2bf(v0) | ((unsigned)f2bf(v1) << 16);
                pk.y = (unsigned)f2bf(v2);
                ((uint2*)xs)[idx] = pk;
            }
        }
        __syncthreads();
        #pragma unroll 2
        for (int xT = 0; xT < 4; ++xT) {
            int xb = xT * 16 + xl + 1;
            float pv[4], vo[4];
            #pragma unroll
            for (int r = 0; r < 4; ++r) {
                int ly = w * 4 + r + 1;
                const uint2* base = (const uint2*)xs;
                uint2 ua = base[(ly + dy0) * 66 + xb + dx0];
                uint2 ub = base[(ly + dy1) * 66 + xb + dx1];
                uint2 uc = base[(ly + 1) * 66 + xb + 1];
                f32x4 acc = (f32x4){0.f, 0.f, 0.f, 0.f};
                acc = __builtin_amdgcn_mfma_f32_16x16x32_bf16(A10, mk8(ua, ub), acc, 0, 0, 0);
                acc = __builtin_amdgcn_mfma_f32_16x16x32_bf16(A11, mk8(uc, uc), acc, 0, 0, 0);
                #pragma unroll
                for (int reg = 0; reg < 4; ++reg) {
                    float val = fmaxf(acc[reg] * inv1[reg] + bs1[reg], 0.f);
                    if (r & 1) {
                        float vm = fmaxf(val, pv[reg]);
                        vo[reg] = fmaxf(vm, __shfl_xor(vm, 1, 64));
                    } else {
                        pv[reg] = val;
                    }
                }
                if ((r & 1) && !(lane & 1)) {
                    int py = h * 16 + w * 2 + (r >> 1);
                    int px = xT * 8 + (xl >> 1);
                    int pos = (py + 1) * 34 + (px + 1);
                    unsigned u0 = (unsigned)f2bf(vo[0]) | ((unsigned)f2bf(vo[1]) << 16);
                    unsigned u1 = (unsigned)f2bf(vo[2]) | ((unsigned)f2bf(vo[3]) << 16);
                    unsigned* hp = h1w + pos * 4 + (q & 1) * 2;
                    hp[0] = u0; hp[1] = u1;
                }
            }
        }
    }
    __syncthreads();

    // zero h2t borders (68 pos x 4 arrays) -- read only after next barrier
    if (t < 272) {
        int arr = t & 3, idx = t >> 2;
        int y, xx;
        if (idx < 18)      { y = 0;        xx = idx; }
        else if (idx < 36) { y = 17;       xx = idx - 18; }
        else if (idx < 52) { y = idx - 35; xx = 0; }
        else               { y = idx - 51; xx = 17; }
        uint4 z = {0u, 0u, 0u, 0u};
        *(uint4*)(h2t + arr * 2592 + (y * 18 + xx) * 8) = z;
    }

    // ======== conv2 (32x32x16): 16->32, pool -> h2t bordered ========
    {
        int n = lane & 31, kh = lane >> 5;
        const unsigned short* h1r = kh ? h1B : h1A;
        f32x16 acc2[4];
        #pragma unroll
        for (int r = 0; r < 4; ++r) acc2[r] = (f32x16)(0.f);
        #pragma unroll
        for (int tap = 0; tap < 9; ++tap) {
            short8 A = *(const short8*)(wp2 + ((tap * 64 + lane) << 3));
            int dy = tap / 3 - 1, dx = tap % 3 - 1;
            int pbase = (w * 4 + dy + 1) * 34 + (n + dx + 1);
            #pragma unroll
            for (int r = 0; r < 4; ++r) {
                short8 B = *(const short8*)(h1r + (pbase + r * 34) * 8);
                acc2[r] = __builtin_amdgcn_mfma_f32_32x32x16_bf16(A, B, acc2[r], 0, 0, 0);
            }
        }
        #pragma unroll
        for (int g = 0; g < 4; ++g) {
            int oc0 = g * 8 + kh * 4;
            float4 inv = *(const float4*)&cst2[oc0];
            float4 bsv = *(const float4*)&cst2[32 + oc0];
            #pragma unroll
            for (int rg = 0; rg < 2; ++rg) {
                float vo[4];
                #pragma unroll
                for (int j = 0; j < 4; ++j) {
                    int reg = g * 4 + j;
                    float iv = ((const float*)&inv)[j], bv = ((const float*)&bsv)[j];
                    float v0 = fmaxf(acc2[rg * 2][reg] * iv + bv, 0.f);
                    float v1 = fmaxf(acc2[rg * 2 + 1][reg] * iv + bv, 0.f);
                    float vm = fmaxf(v0, v1);
                    vo[j] = fmaxf(vm, __shfl_xor(vm, 1, 64));
                }
                if (!(n & 1)) {
                    int py = w * 2 + rg, px = n >> 1;
                    int pos = (py + 1) * 18 + (px + 1);
                    unsigned u0 = (unsigned)f2bf(vo[0]) | ((unsigned)f2bf(vo[1]) << 16);
                    unsigned u1 = (unsigned)f2bf(vo[2]) | ((unsigned)f2bf(vo[3]) << 16);
                    unsigned* hp = (unsigned*)(h2t + g * 2592 + pos * 8 + kh * 4);
                    hp[0] = u0; hp[1] = u1;
                }
            }
        }
    }
    __syncthreads();

    // ======== conv3 (32x32x16): 32->64, pool -> feats [64 pos][68] f32 ========
    {
        int n = lane & 31, kh = lane >> 5;
        int yr = n >> 4, px_ = n & 15;
        f32x16 acc3[2];
        acc3[0] = (f32x16)(0.f);
        acc3[1] = (f32x16)(0.f);
        #pragma unroll
        for (int tap = 0; tap < 9; ++tap) {
            int dy = tap / 3 - 1, dx = tap % 3 - 1;
            int pos = (2 * w + yr + dy + 1) * 18 + (px_ + dx + 1);
            #pragma unroll
            for (int h = 0; h < 2; ++h) {
                short8 B = *(const short8*)(h2t + (h * 2 + kh) * 2592 + pos * 8);
                short8 A0 = *(const short8*)(wp3 + ((((tap * 2 + h) * 2 + 0) * 64 + lane) << 3));
                short8 A1 = *(const short8*)(wp3 + ((((tap * 2 + h) * 2 + 1) * 64 + lane) << 3));
                acc3[0] = __builtin_amdgcn_mfma_f32_32x32x16_bf16(A0, B, acc3[0], 0, 0, 0);
                acc3[1] = __builtin_amdgcn_mfma_f32_32x32x16_bf16(A1, B, acc3[1], 0, 0, 0);
            }
        }
        #pragma unroll
        for (int ot = 0; ot < 2; ++ot)
            #pragma unroll
            for (int g = 0; g < 4; ++g) {
                int oc0 = ot * 32 + g * 8 + kh * 4;
                float4 inv = *(const float4*)&cst3[oc0];
                float4 bsv = *(const float4*)&cst3[64 + oc0];
                float vo[4];
                #pragma unroll
                for (int j = 0; j < 4; ++j) {
                    int reg = g * 4 + j;
                    float iv = ((const float*)&inv)[j], bv = ((const float*)&bsv)[j];
                    float v = fmaxf(acc3[ot][reg] * iv + bv, 0.f);
                    float vy = fmaxf(v, __shfl_xor(v, 16, 64));
                    vo[j] = fmaxf(vy, __shfl_xor(vy, 1, 64));
                }
                if (!(n & 17)) {   // n even, yr==0
                    int pos = w * 8 + (px_ >> 1);
                    float4 pk = {vo[0], vo[1], vo[2], vo[3]};
                    *(float4*)&feats[pos * 68 + oc0] = pk;
                }
            }
    }
    __syncthreads();

    // ======== head: projection + tanh + analytic quantum map + classifier ========
    if (t < 128) {
        int k = t >> 3, d = t & 7;
        const float4* wrow = (const float4*)(pjwt + ((k * 8 + d) << 8));
        float zacc = 0.f;
        #pragma unroll 4
        for (int pos = 0; pos < 64; ++pos) {
            float4 wv = wrow[pos];
            float4 fv = *(const float4*)&feats[pos * 68 + k * 4];
            zacc = fmaf(wv.x, fv.x, zacc);
            zacc = fmaf(wv.y, fv.y, zacc);
            zacc = fmaf(wv.z, fv.z, zacc);
            zacc = fmaf(wv.w, fv.w, zacc);
        }
        float z = zacc + pjb[k * 8 + d];
        czs[k * 8 + d] = cosf(0.5f * tanhf(z));
    }
    __syncthreads();
    if (t < 160) {
        int k = t / 10, c = t - (t / 10) * 10;
        float cz[8];
        #pragma unroll
        for (int i = 0; i < 8; ++i) cz[i] = czs[k * 8 + i];
        const float* cwp = cw + c * 576 + k * 36;
        float s = 0.f;
        float pp = 1.f;
        #pragma unroll
        for (int i = 0; i < 8; ++i) { pp *= cz[i]; s = fmaf(pp, cwp[i], s); }
        int cnt = 8;
        #pragma unroll
        for (int i = 0; i < 8; ++i) {
            float p2 = 1.f;
            #pragma unroll
            for (int j = i + 1; j < 8; ++j) { p2 *= cz[j]; s = fmaf(p2, cwp[cnt++], s); }
        }
        partl[k * 10 + c] = s;
    }
    __syncthreads();
    if (t < 10) {
        float s = cbias[t];
        #pragma unroll
        for (int k = 0; k < 16; ++k) s += partl[k * 10 + t];
        out[b * 10 + t] = s;
    }
}

extern "C" void kernel_launch(void* const* d_in, const int* in_sizes, int n_in,
                              void* d_out, int out_size, void* d_ws, size_t ws_size,
                              hipStream_t stream) {
    const float* x     = (const float*)d_in[0];
    const float* c1w   = (const float*)d_in[1];
    const float* c1b   = (const float*)d_in[2];
    const float* b1g   = (const float*)d_in[3];
    const float* b1b   = (const float*)d_in[4];
    const float* b1m   = (const float*)d_in[5];
    const float* b1v   = (const float*)d_in[6];
    const float* c2w   = (const float*)d_in[7];
    const float* c2b   = (const float*)d_in[8];
    const float* b2g   = (const float*)d_in[9];
    const float* b2b   = (const float*)d_in[10];
    const float* b2m   = (const float*)d_in[11];
    const float* b2v   = (const float*)d_in[12];
    const float* c3w   = (const float*)d_in[13];
    const float* c3b   = (const float*)d_in[14];
    const float* b3g   = (const float*)d_in[15];
    const float* b3b   = (const float*)d_in[16];
    const float* b3m   = (const float*)d_in[17];
    const float* b3v   = (const float*)d_in[18];
    const float* pjw   = (const float*)d_in[19];
    const float* pjb   = (const float*)d_in[20];
    const float* cw    = (const float*)d_in[21];
    const float* cbias = (const float*)d_in[22];
    float* outp = (float*)d_out;

    unsigned char* prep = (unsigned char*)d_ws;
    unsigned short* wp2 = (unsigned short*)prep;                       // 4608 bf16
    unsigned short* wp3 = (unsigned short*)(prep + 16384);             // 18432 bf16
    unsigned short* wp1 = (unsigned short*)(prep + 16384 + 36864);     // 1024 bf16
    float* cst2 = (float*)(prep + 16384 + 36864 + 2048);               // 64 f
    float* cst3 = cst2 + 64;                                           // 128 f
    float* cst1 = cst3 + 128;                                          // 32 f
    float* pjwt = (float*)(prep + 16384 + 36864 + 2048 + 1024);        // 32768 f

    k_prep<<<223, 256, 0, stream>>>(c2w, c3w, b2g, b2b, b2m, b2v, c2b,
                                    b3g, b3b, b3m, b3v, c3b,
                                    c1w, b1g, b1b, b1m, b1v, c1b, pjw,
                                    wp2, wp3, wp1, cst2, cst3, cst1, pjwt);
    k_fused<<<512, 512, 0, stream>>>(x, wp1, cst1, wp2, cst2, wp3, cst3,
                                     pjwt, pjb, cw, cbias, outp);
}